// Round 6
// baseline (276.831 us; speedup 1.0000x reference)
//
#include <hip/hip_runtime.h>
#include <math.h>

#define DIMC 96
#define DIN  192
#define NST  16
#define RNK  6
#define KD   4
#define HH   64
#define WWD  64
#define LL   4096
#define BB   2
#define NC   256   // number of chunks
#define CH   16    // chunk length (NC*CH == LL)
#define CPK  48    // record floats: B(16) | C(16) | dts(6) | pad(10)

__device__ __forceinline__ int pos_of(int k, int l) {
    int t = ((l & 63) << 6) | (l >> 6);       // 64x64 transpose
    switch (k) {
        case 0: return l;
        case 1: return t;
        case 2: return LL - 1 - l;
        default: return ((((LL-1-l) & 63) << 6) | ((LL-1-l) >> 6));
    }
}

__device__ __forceinline__ float silu_f(float v) {
    return v / (1.f + __expf(-v));
}

// ---------------- K0: weight transposes ----------------
__global__ __launch_bounds__(256) void k0_prep(
    const float* __restrict__ Win, const float* __restrict__ Wout,
    const float* __restrict__ xpw,
    float* __restrict__ WinT, float* __restrict__ WoutT, float* __restrict__ wT3)
{
    int idx = blockIdx.x*256 + threadIdx.x;
    int stride = gridDim.x*256;
    for (int i = idx; i < 96*384; i += stride) {          // WinT[j][o]
        int j = i / 384, o = i - j*384;
        WinT[i] = Win[o*96 + j];
    }
    for (int i = idx; i < 192*96; i += stride) {          // WoutT[j][o]
        int j = i / 96, o = i - j*96;
        WoutT[i] = Wout[o*192 + j];
    }
    for (int i = idx; i < KD*192*CPK; i += stride) {      // wT3[k][j][c']
        int kk = i / (192*CPK); int rem = i - kk*192*CPK;
        int j = rem / CPK, c = rem - j*CPK;
        float v = 0.f;
        if (c < 16)       v = xpw[((size_t)kk*(RNK+2*NST) + RNK + c)*DIN + j];            // B
        else if (c < 32)  v = xpw[((size_t)kk*(RNK+2*NST) + RNK + NST + (c-16))*DIN + j]; // C
        else if (c < 38)  v = xpw[((size_t)kk*(RNK+2*NST) + (c-32))*DIN + j];             // dts
        wT3[i] = v;
    }
}

// ---------------- K1: |x-y|, LN(96), in_proj ----------------
__global__ __launch_bounds__(1024) void k1_ln_inproj(
    const float* __restrict__ x, const float* __restrict__ y,
    const float* __restrict__ lnw, const float* __restrict__ lnb,
    const float* __restrict__ WinT,
    float* __restrict__ diff, float* __restrict__ xm, float* __restrict__ zbuf)
{
    __shared__ float hT[96*65];
    __shared__ float ps1[16*64], ps2[16*64];
    __shared__ float mus[64], rss[64];
    int t = threadIdx.x;
    int ptile = blockIdx.x >> 1, cgrp = blockIdx.x & 1;
    int p0 = ptile*64;

    #pragma unroll
    for (int s = 0; s < 6; s++) {
        int i = t + 1024*s;
        float v = fabsf(x[(size_t)p0*96 + i] - y[(size_t)p0*96 + i]);
        if (cgrp == 0) diff[(size_t)p0*96 + i] = v;
        int pos = i / 96, ch = i - pos*96;
        hT[ch*65 + pos] = v;
    }
    __syncthreads();
    {
        int pos = t & 63, part = t >> 6;
        float s1 = 0.f, s2 = 0.f;
        #pragma unroll
        for (int m = 0; m < 6; m++) {
            float v = hT[(part*6 + m)*65 + pos];
            s1 += v; s2 += v*v;
        }
        ps1[part*64 + pos] = s1; ps2[part*64 + pos] = s2;
    }
    __syncthreads();
    if (t < 64) {
        float S1 = 0.f, S2 = 0.f;
        #pragma unroll
        for (int i = 0; i < 16; i++) { S1 += ps1[i*64 + t]; S2 += ps2[i*64 + t]; }
        float mu = S1 * (1.f/96.f);
        float var = S2 * (1.f/96.f) - mu*mu;
        mus[t] = mu; rss[t] = rsqrtf(var + 1e-5f);
    }
    __syncthreads();
    #pragma unroll
    for (int s = 0; s < 6; s++) {
        int i = t + 1024*s;
        int pos = i / 96, ch = i - pos*96;
        hT[ch*65 + pos] = (hT[ch*65 + pos] - mus[pos]) * rss[pos] * lnw[ch] + lnb[ch];
    }
    __syncthreads();

    int w = __builtin_amdgcn_readfirstlane(t >> 6);
    int lane = t & 63;
    int c0 = cgrp*192 + w*12;
    const float* wp = WinT + c0;
    float acc[12];
    #pragma unroll
    for (int cc = 0; cc < 12; cc++) acc[cc] = 0.f;
    #pragma unroll 2
    for (int j = 0; j < 96; j++) {
        float u = hT[j*65 + lane];
        const float* wrow = wp + j*384;
        #pragma unroll
        for (int cc = 0; cc < 12; cc++) acc[cc] += u * wrow[cc];
    }
    size_t p = (size_t)(p0 + lane);
    float* dst = (c0 < 192) ? (xm + p*192 + c0) : (zbuf + p*192 + (c0 - 192));
    #pragma unroll
    for (int q = 0; q < 3; q++)
        *(float4*)&dst[4*q] = make_float4(acc[4*q], acc[4*q+1], acc[4*q+2], acc[4*q+3]);
}

// ---------------- K2: depthwise 3x3 conv + bias + SiLU ----------------
__global__ __launch_bounds__(192) void k2_conv(
    const float* __restrict__ xm, const float* __restrict__ cw,
    const float* __restrict__ cb, float* __restrict__ xconv)
{
    int p = blockIdx.x;
    int d = threadIdx.x;
    int b = p >> 12;
    int l = p & (LL - 1);
    int hh = l >> 6, ww = l & 63;
    float acc = cb[d];
    const float* wd = cw + d*9;
    #pragma unroll
    for (int di = -1; di <= 1; di++) {
        int h2 = hh + di;
        if ((unsigned)h2 < HH) {
            #pragma unroll
            for (int dj = -1; dj <= 1; dj++) {
                int w2 = ww + dj;
                if ((unsigned)w2 < WWD)
                    acc += wd[(di+1)*3 + (dj+1)] * xm[((size_t)b*LL + h2*WWD + w2)*DIN + d];
            }
        }
    }
    xconv[(size_t)p*DIN + d] = silu_f(acc);
}

// ---------------- K3: fused 4-direction x_proj -> XDK[bk][l][48] (sequence-major) ----------------
__global__ __launch_bounds__(512) void k3_xproj(
    const float* __restrict__ xconv, const float* __restrict__ wT3,
    float* __restrict__ XDK)
{
    __shared__ float uT[192*65];
    int t = threadIdx.x;
    int ptile = blockIdx.x >> 1, wgrp = blockIdx.x & 1;
    int p0 = ptile*64;

    #pragma unroll
    for (int s = 0; s < 24; s++) {
        int i = t + 512*s;
        int pos = i / 192, ch = i - pos*192;
        uT[ch*65 + pos] = xconv[(size_t)(p0 + pos)*192 + ch];
    }
    __syncthreads();

    int w = __builtin_amdgcn_readfirstlane(t >> 6);   // 0..7
    int slot = wgrp*8 + w;                             // 0..15
    int k = slot >> 2, cq = slot & 3;
    int lane = t & 63;
    int c0 = cq*12;
    const float* wp = wT3 + (size_t)k*192*CPK + c0;
    float acc[12];
    #pragma unroll
    for (int cc = 0; cc < 12; cc++) acc[cc] = 0.f;
    #pragma unroll 2
    for (int j = 0; j < 192; j++) {
        float u = uT[j*65 + lane];
        const float* wrow = wp + j*CPK;
        #pragma unroll
        for (int cc = 0; cc < 12; cc++) acc[cc] += u * wrow[cc];
    }
    int p = p0 + lane;
    int b = p >> 12;
    int s = p & (LL - 1);
    int ts = ((s & 63) << 6) | (s >> 6);
    int l;
    switch (k) {
        case 0: l = s; break;
        case 1: l = ts; break;
        case 2: l = LL - 1 - s; break;
        default: l = LL - 1 - ts; break;
    }
    float* dst = XDK + ((size_t)(b*KD + k)*LL + l)*CPK + c0;
    #pragma unroll
    for (int q = 0; q < 3; q++)
        *(float4*)&dst[4*q] = make_float4(acc[4*q], acc[4*q+1], acc[4*q+2], acc[4*q+3]);
}

// ---------------- K4: scan pass A — h over chunk + S = sum(delta) ----------------
__global__ __launch_bounds__(192) void k4_scanA(
    const float* __restrict__ xconv, const float* __restrict__ XDK,
    const float* __restrict__ dtw, const float* __restrict__ dtb,
    const float* __restrict__ A_log,
    float* __restrict__ Sarr, float* __restrict__ Q)
{
    int blk = blockIdx.x;              // bk*NC + c
    int c  = blk & (NC - 1);
    int bk = blk >> 8;
    int k  = bk & 3;
    int b  = bk >> 2;
    int d  = threadIdx.x;
    float dw[RNK];
    #pragma unroll
    for (int r = 0; r < RNK; r++) dw[r] = dtw[((size_t)k*DIN + d)*RNK + r];
    float bias = dtb[k*DIN + d];
    float A[NST];
    #pragma unroll
    for (int n = 0; n < NST; n++) A[n] = -__expf(A_log[((size_t)k*DIN + d)*NST + n]);
    bool fastA = true;
    #pragma unroll
    for (int n = 1; n < NST; n++)
        fastA = fastA && (fabsf(A[n] - (float)(n+1)*A[0]) <= 1e-4f*(float)(n+1));

    float h[NST];
    #pragma unroll
    for (int n = 0; n < NST; n++) h[n] = 0.f;
    float S = 0.f;

    size_t rb = ((size_t)bk*LL + c*CH)*CPK;
    if (fastA) {
        #pragma unroll 2
        for (int step = 0; step < CH; step++) {
            const float* rec = XDK + rb + step*CPK;
            float dl = bias;
            #pragma unroll
            for (int r = 0; r < RNK; r++) dl += rec[32 + r] * dw[r];
            dl = (dl > 20.f) ? dl : __logf(1.f + __expf(dl));
            int l = c*CH + step;
            float uu = xconv[((size_t)b*LL + pos_of(k, l))*DIN + d];
            float du = dl * uu;
            S += dl;
            float e1 = __expf(dl * A[0]);
            float a = e1;
            #pragma unroll
            for (int n = 0; n < NST; n++) {
                h[n] = a*h[n] + du*rec[n];
                a *= e1;
            }
        }
    } else {
        #pragma unroll 2
        for (int step = 0; step < CH; step++) {
            const float* rec = XDK + rb + step*CPK;
            float dl = bias;
            #pragma unroll
            for (int r = 0; r < RNK; r++) dl += rec[32 + r] * dw[r];
            dl = (dl > 20.f) ? dl : __logf(1.f + __expf(dl));
            int l = c*CH + step;
            float uu = xconv[((size_t)b*LL + pos_of(k, l))*DIN + d];
            float du = dl * uu;
            S += dl;
            #pragma unroll
            for (int n = 0; n < NST; n++) {
                float a = __expf(dl * A[n]);
                h[n] = a*h[n] + du*rec[n];
            }
        }
    }
    Sarr[(size_t)blk*DIN + d] = S;
    size_t qb = (size_t)blk*NST*DIN + d;
    #pragma unroll
    for (int n = 0; n < NST; n++) Q[qb + n*DIN] = h[n];
}

// ---------------- K5: compose chunk transfers; Q becomes per-chunk init state ----------------
__global__ __launch_bounds__(256) void k5_scanB(
    const float* __restrict__ A_log, const float* __restrict__ Sarr,
    float* __restrict__ Q)
{
    int idx = blockIdx.x*256 + threadIdx.x;
    if (idx >= BB*KD*NST*DIN) return;
    int d = idx % DIN;
    int rest = idx / DIN;
    int n = rest % NST; rest /= NST;
    int k = rest & 3;
    int b = rest >> 2;
    int bk = b*KD + k;
    float A = -__expf(A_log[((size_t)k*DIN + d)*NST + n]);
    size_t qstride = (size_t)NST*DIN;
    size_t qbase = (size_t)bk*NC*qstride + n*DIN + d;
    size_t sbase = (size_t)bk*NC*DIN + d;
    float h = 0.f;
    #pragma unroll 4
    for (int c = 0; c < NC; c++) {
        float s = Sarr[sbase + c*DIN];
        float q = Q[qbase + c*qstride];
        Q[qbase + c*qstride] = h;
        h = __expf(A*s)*h + q;
    }
}

// ---------------- K6: scan pass C — replay, emit y at SPATIAL position ----------------
__global__ __launch_bounds__(192) void k6_scanC(
    const float* __restrict__ xconv, const float* __restrict__ XDK,
    const float* __restrict__ dtw, const float* __restrict__ dtb,
    const float* __restrict__ A_log, const float* __restrict__ Ds,
    const float* __restrict__ Q, float* __restrict__ outy)
{
    int blk = blockIdx.x;
    int c  = blk & (NC - 1);
    int bk = blk >> 8;
    int k  = bk & 3;
    int b  = bk >> 2;
    int d  = threadIdx.x;
    float dw[RNK];
    #pragma unroll
    for (int r = 0; r < RNK; r++) dw[r] = dtw[((size_t)k*DIN + d)*RNK + r];
    float bias = dtb[k*DIN + d];
    float A[NST];
    #pragma unroll
    for (int n = 0; n < NST; n++) A[n] = -__expf(A_log[((size_t)k*DIN + d)*NST + n]);
    bool fastA = true;
    #pragma unroll
    for (int n = 1; n < NST; n++)
        fastA = fastA && (fabsf(A[n] - (float)(n+1)*A[0]) <= 1e-4f*(float)(n+1));
    float h[NST];
    size_t qb = (size_t)blk*NST*DIN + d;
    #pragma unroll
    for (int n = 0; n < NST; n++) h[n] = Q[qb + n*DIN];
    float Dv = Ds[k*DIN + d];

    size_t rb = ((size_t)bk*LL + c*CH)*CPK;
    if (fastA) {
        #pragma unroll 2
        for (int step = 0; step < CH; step++) {
            const float* rec = XDK + rb + step*CPK;
            float dl = bias;
            #pragma unroll
            for (int r = 0; r < RNK; r++) dl += rec[32 + r] * dw[r];
            dl = (dl > 20.f) ? dl : __logf(1.f + __expf(dl));
            int l = c*CH + step;
            int sp = pos_of(k, l);
            float uu = xconv[((size_t)b*LL + sp)*DIN + d];
            float du = dl * uu;
            float e1 = __expf(dl * A[0]);
            float a = e1;
            float yv = 0.f;
            #pragma unroll
            for (int n = 0; n < NST; n++) {
                h[n] = a*h[n] + du*rec[n];
                yv += h[n] * rec[16 + n];
                a *= e1;
            }
            outy[((size_t)bk*LL + sp)*DIN + d] = yv + Dv*uu;
        }
    } else {
        #pragma unroll 2
        for (int step = 0; step < CH; step++) {
            const float* rec = XDK + rb + step*CPK;
            float dl = bias;
            #pragma unroll
            for (int r = 0; r < RNK; r++) dl += rec[32 + r] * dw[r];
            dl = (dl > 20.f) ? dl : __logf(1.f + __expf(dl));
            int l = c*CH + step;
            int sp = pos_of(k, l);
            float uu = xconv[((size_t)b*LL + sp)*DIN + d];
            float du = dl * uu;
            float yv = 0.f;
            #pragma unroll
            for (int n = 0; n < NST; n++) {
                float a = __expf(dl * A[n]);
                h[n] = a*h[n] + du*rec[n];
                yv += h[n] * rec[16 + n];
            }
            outy[((size_t)bk*LL + sp)*DIN + d] = yv + Dv*uu;
        }
    }
}

// ---------------- K7: combine (coalesced), LN(192), gate, out_proj, residual ----------------
__global__ __launch_bounds__(256) void k7_out(
    const float* __restrict__ outy, const float* __restrict__ zbuf,
    const float* __restrict__ diff, const float* __restrict__ onw,
    const float* __restrict__ onb, const float* __restrict__ WoutT,
    float* __restrict__ out)
{
    __shared__ float gT[192*65];
    __shared__ float ps1[4*64], ps2[4*64];
    __shared__ float mus[64], rss[64];
    int t = threadIdx.x;
    int ptile = blockIdx.x >> 1, chalf = blockIdx.x & 1;
    int p0 = ptile*64;
    int b = p0 >> 12;
    int l0 = p0 & (LL - 1);
    const size_t seg = (size_t)LL*DIN;
    size_t base = ((size_t)(b*KD)*LL + l0)*DIN;

    #pragma unroll
    for (int s = 0; s < 48; s++) {
        int i = t + 256*s;
        float yc = outy[base + i] + outy[base + seg + i]
                 + outy[base + 2*seg + i] + outy[base + 3*seg + i];
        int pos = i / 192, ch = i - pos*192;
        gT[ch*65 + pos] = yc;
    }
    __syncthreads();
    {
        int pos = t & 63, part = t >> 6;
        float s1 = 0.f, s2 = 0.f;
        #pragma unroll
        for (int m = 0; m < 48; m++) {
            float v = gT[(part*48 + m)*65 + pos];
            s1 += v; s2 += v*v;
        }
        ps1[part*64 + pos] = s1; ps2[part*64 + pos] = s2;
    }
    __syncthreads();
    if (t < 64) {
        float S1 = ps1[t] + ps1[64+t] + ps1[128+t] + ps1[192+t];
        float S2 = ps2[t] + ps2[64+t] + ps2[128+t] + ps2[192+t];
        float mu = S1 * (1.f/192.f);
        float var = S2 * (1.f/192.f) - mu*mu;
        mus[t] = mu; rss[t] = rsqrtf(var + 1e-5f);
    }
    __syncthreads();
    #pragma unroll
    for (int s = 0; s < 48; s++) {
        int i = t + 256*s;
        int pos = i / 192, ch = i - pos*192;
        float v = gT[ch*65 + pos];
        float yn = (v - mus[pos]) * rss[pos] * onw[ch] + onb[ch];
        float z = zbuf[(size_t)p0*DIN + i];
        gT[ch*65 + pos] = yn * silu_f(z);
    }
    __syncthreads();

    int w = __builtin_amdgcn_readfirstlane(t >> 6);
    int lane = t & 63;
    int c0 = chalf*48 + w*12;
    const float* wp = WoutT + c0;
    float acc[12];
    #pragma unroll
    for (int cc = 0; cc < 12; cc++) acc[cc] = 0.f;
    #pragma unroll 2
    for (int j = 0; j < 192; j++) {
        float u = gT[j*65 + lane];
        const float* wrow = wp + j*96;
        #pragma unroll
        for (int cc = 0; cc < 12; cc++) acc[cc] += u * wrow[cc];
    }
    size_t p = (size_t)(p0 + lane);
    #pragma unroll
    for (int q = 0; q < 3; q++) {
        float4 dv = *(const float4*)&diff[p*96 + c0 + 4*q];
        *(float4*)&out[p*96 + c0 + 4*q] =
            make_float4(acc[4*q] + dv.x, acc[4*q+1] + dv.y, acc[4*q+2] + dv.z, acc[4*q+3] + dv.w);
    }
}

extern "C" void kernel_launch(void* const* d_in, const int* in_sizes, int n_in,
                              void* d_out, int out_size, void* d_ws, size_t ws_size,
                              hipStream_t stream)
{
    const float* x       = (const float*)d_in[0];
    const float* y       = (const float*)d_in[1];
    const float* ln_w    = (const float*)d_in[2];
    const float* ln_b    = (const float*)d_in[3];
    const float* in_proj = (const float*)d_in[4];
    const float* conv_w  = (const float*)d_in[5];
    const float* conv_b  = (const float*)d_in[6];
    const float* x_proj  = (const float*)d_in[7];
    const float* dt_w    = (const float*)d_in[8];
    const float* dt_b    = (const float*)d_in[9];
    const float* A_log   = (const float*)d_in[10];
    const float* Ds      = (const float*)d_in[11];
    const float* onw     = (const float*)d_in[12];
    const float* onb     = (const float*)d_in[13];
    const float* out_w   = (const float*)d_in[14];
    float* out = (float*)d_out;

    float* ws    = (float*)d_ws;
    float* diff  = ws;                       // 786432
    float* zbuf  = diff  + 786432;           // 1572864
    float* xm    = zbuf  + 1572864;          // 1572864
    float* xconv = xm    + 1572864;          // 1572864
    float* XDK   = xconv + 1572864;          // 1572864
    float* outy  = XDK   + 1572864;          // 6291456
    float* Qbuf  = outy  + 6291456;          // 6291456 (2048 blk x 16 x 192)
    float* Sarr  = Qbuf  + 6291456;          // 393216  (2048 blk x 192)
    float* WinT  = Sarr  + 393216;           // 36864
    float* WoutT = WinT  + 36864;            // 18432
    float* wT3   = WoutT + 18432;            // 36864

    const int BL = BB * LL;                  // 8192

    hipLaunchKernelGGL(k0_prep, dim3(144), dim3(256), 0, stream,
                       in_proj, out_w, x_proj, WinT, WoutT, wT3);
    hipLaunchKernelGGL(k1_ln_inproj, dim3(BL/64*2), dim3(1024), 0, stream,
                       x, y, ln_w, ln_b, WinT, diff, xm, zbuf);
    hipLaunchKernelGGL(k2_conv, dim3(BL), dim3(DIN), 0, stream,
                       xm, conv_w, conv_b, xconv);
    hipLaunchKernelGGL(k3_xproj, dim3(BL/64*2), dim3(512), 0, stream,
                       xconv, wT3, XDK);
    hipLaunchKernelGGL(k4_scanA, dim3(BB*KD*NC), dim3(DIN), 0, stream,
                       xconv, XDK, dt_w, dt_b, A_log, Sarr, Qbuf);
    hipLaunchKernelGGL(k5_scanB, dim3((BB*KD*NST*DIN + 255)/256), dim3(256), 0, stream,
                       A_log, Sarr, Qbuf);
    hipLaunchKernelGGL(k6_scanC, dim3(BB*KD*NC), dim3(DIN), 0, stream,
                       xconv, XDK, dt_w, dt_b, A_log, Ds, Qbuf, outy);
    hipLaunchKernelGGL(k7_out, dim3(BL/64*2), dim3(256), 0, stream,
                       outy, zbuf, diff, onw, onb, WoutT, out);
}

// Round 7
// 266.316 us; speedup vs baseline: 1.0395x; 1.0395x over previous
//
#include <hip/hip_runtime.h>
#include <math.h>

#define DIMC 96
#define DIN  192
#define NST  16
#define RNK  6
#define KD   4
#define HH   64
#define WWD  64
#define LL   4096
#define BB   2
#define NC   128   // number of chunks
#define CH   32    // chunk length (NC*CH == LL)
#define CPK  48    // record floats: B(16) | C(16) | dts(6) | pad(10)

__device__ __forceinline__ int pos_of(int k, int l) {
    int t = ((l & 63) << 6) | (l >> 6);       // 64x64 transpose
    switch (k) {
        case 0: return l;
        case 1: return t;
        case 2: return LL - 1 - l;
        default: return ((((LL-1-l) & 63) << 6) | ((LL-1-l) >> 6));
    }
}

__device__ __forceinline__ float silu_f(float v) {
    return v / (1.f + __expf(-v));
}

// ---------------- K0: weight transposes ----------------
__global__ __launch_bounds__(256) void k0_prep(
    const float* __restrict__ Win, const float* __restrict__ Wout,
    const float* __restrict__ xpw,
    float* __restrict__ WinT, float* __restrict__ WoutT, float* __restrict__ wT3)
{
    int idx = blockIdx.x*256 + threadIdx.x;
    int stride = gridDim.x*256;
    for (int i = idx; i < 96*384; i += stride) {          // WinT[j][o]
        int j = i / 384, o = i - j*384;
        WinT[i] = Win[o*96 + j];
    }
    for (int i = idx; i < 192*96; i += stride) {          // WoutT[j][o]
        int j = i / 96, o = i - j*96;
        WoutT[i] = Wout[o*192 + j];
    }
    for (int i = idx; i < KD*192*CPK; i += stride) {      // wT3[k][j][c']
        int kk = i / (192*CPK); int rem = i - kk*192*CPK;
        int j = rem / CPK, c = rem - j*CPK;
        float v = 0.f;
        if (c < 16)       v = xpw[((size_t)kk*(RNK+2*NST) + RNK + c)*DIN + j];            // B
        else if (c < 32)  v = xpw[((size_t)kk*(RNK+2*NST) + RNK + NST + (c-16))*DIN + j]; // C
        else if (c < 38)  v = xpw[((size_t)kk*(RNK+2*NST) + (c-32))*DIN + j];             // dts
        wT3[i] = v;
    }
}

// ---------------- K1: |x-y|, LN(96), in_proj ----------------
__global__ __launch_bounds__(1024) void k1_ln_inproj(
    const float* __restrict__ x, const float* __restrict__ y,
    const float* __restrict__ lnw, const float* __restrict__ lnb,
    const float* __restrict__ WinT,
    float* __restrict__ diff, float* __restrict__ xm, float* __restrict__ zbuf)
{
    __shared__ float hT[96*65];
    __shared__ float ps1[16*64], ps2[16*64];
    __shared__ float mus[64], rss[64];
    int t = threadIdx.x;
    int ptile = blockIdx.x >> 1, cgrp = blockIdx.x & 1;
    int p0 = ptile*64;

    #pragma unroll
    for (int s = 0; s < 6; s++) {
        int i = t + 1024*s;
        float v = fabsf(x[(size_t)p0*96 + i] - y[(size_t)p0*96 + i]);
        if (cgrp == 0) diff[(size_t)p0*96 + i] = v;
        int pos = i / 96, ch = i - pos*96;
        hT[ch*65 + pos] = v;
    }
    __syncthreads();
    {
        int pos = t & 63, part = t >> 6;
        float s1 = 0.f, s2 = 0.f;
        #pragma unroll
        for (int m = 0; m < 6; m++) {
            float v = hT[(part*6 + m)*65 + pos];
            s1 += v; s2 += v*v;
        }
        ps1[part*64 + pos] = s1; ps2[part*64 + pos] = s2;
    }
    __syncthreads();
    if (t < 64) {
        float S1 = 0.f, S2 = 0.f;
        #pragma unroll
        for (int i = 0; i < 16; i++) { S1 += ps1[i*64 + t]; S2 += ps2[i*64 + t]; }
        float mu = S1 * (1.f/96.f);
        float var = S2 * (1.f/96.f) - mu*mu;
        mus[t] = mu; rss[t] = rsqrtf(var + 1e-5f);
    }
    __syncthreads();
    #pragma unroll
    for (int s = 0; s < 6; s++) {
        int i = t + 1024*s;
        int pos = i / 96, ch = i - pos*96;
        hT[ch*65 + pos] = (hT[ch*65 + pos] - mus[pos]) * rss[pos] * lnw[ch] + lnb[ch];
    }
    __syncthreads();

    int w = __builtin_amdgcn_readfirstlane(t >> 6);
    int lane = t & 63;
    int c0 = cgrp*192 + w*12;
    const float* wp = WinT + c0;
    float acc[12];
    #pragma unroll
    for (int cc = 0; cc < 12; cc++) acc[cc] = 0.f;
    #pragma unroll 2
    for (int j = 0; j < 96; j++) {
        float u = hT[j*65 + lane];
        const float* wrow = wp + j*384;
        #pragma unroll
        for (int cc = 0; cc < 12; cc++) acc[cc] += u * wrow[cc];
    }
    size_t p = (size_t)(p0 + lane);
    float* dst = (c0 < 192) ? (xm + p*192 + c0) : (zbuf + p*192 + (c0 - 192));
    #pragma unroll
    for (int q = 0; q < 3; q++)
        *(float4*)&dst[4*q] = make_float4(acc[4*q], acc[4*q+1], acc[4*q+2], acc[4*q+3]);
}

// ---------------- K2: depthwise 3x3 conv + bias + SiLU ----------------
__global__ __launch_bounds__(192) void k2_conv(
    const float* __restrict__ xm, const float* __restrict__ cw,
    const float* __restrict__ cb, float* __restrict__ xconv)
{
    int p = blockIdx.x;
    int d = threadIdx.x;
    int b = p >> 12;
    int l = p & (LL - 1);
    int hh = l >> 6, ww = l & 63;
    float acc = cb[d];
    const float* wd = cw + d*9;
    #pragma unroll
    for (int di = -1; di <= 1; di++) {
        int h2 = hh + di;
        if ((unsigned)h2 < HH) {
            #pragma unroll
            for (int dj = -1; dj <= 1; dj++) {
                int w2 = ww + dj;
                if ((unsigned)w2 < WWD)
                    acc += wd[(di+1)*3 + (dj+1)] * xm[((size_t)b*LL + h2*WWD + w2)*DIN + d];
            }
        }
    }
    xconv[(size_t)p*DIN + d] = silu_f(acc);
}

// ---------------- K3: fused 4-direction x_proj -> XDK[bk][l][48] (sequence-major) ----------------
__global__ __launch_bounds__(512) void k3_xproj(
    const float* __restrict__ xconv, const float* __restrict__ wT3,
    float* __restrict__ XDK)
{
    __shared__ float uT[192*65];
    int t = threadIdx.x;
    int ptile = blockIdx.x >> 1, wgrp = blockIdx.x & 1;
    int p0 = ptile*64;

    #pragma unroll
    for (int s = 0; s < 24; s++) {
        int i = t + 512*s;
        int pos = i / 192, ch = i - pos*192;
        uT[ch*65 + pos] = xconv[(size_t)(p0 + pos)*192 + ch];
    }
    __syncthreads();

    int w = __builtin_amdgcn_readfirstlane(t >> 6);   // 0..7
    int slot = wgrp*8 + w;                             // 0..15
    int k = slot >> 2, cq = slot & 3;
    int lane = t & 63;
    int c0 = cq*12;
    const float* wp = wT3 + (size_t)k*192*CPK + c0;
    float acc[12];
    #pragma unroll
    for (int cc = 0; cc < 12; cc++) acc[cc] = 0.f;
    #pragma unroll 2
    for (int j = 0; j < 192; j++) {
        float u = uT[j*65 + lane];
        const float* wrow = wp + j*CPK;
        #pragma unroll
        for (int cc = 0; cc < 12; cc++) acc[cc] += u * wrow[cc];
    }
    int p = p0 + lane;
    int b = p >> 12;
    int s = p & (LL - 1);
    int ts = ((s & 63) << 6) | (s >> 6);
    int l;
    switch (k) {
        case 0: l = s; break;
        case 1: l = ts; break;
        case 2: l = LL - 1 - s; break;
        default: l = LL - 1 - ts; break;
    }
    float* dst = XDK + ((size_t)(b*KD + k)*LL + l)*CPK + c0;
    #pragma unroll
    for (int q = 0; q < 3; q++)
        *(float4*)&dst[4*q] = make_float4(acc[4*q], acc[4*q+1], acc[4*q+2], acc[4*q+3]);
}

// ---------------- K4: scan pass A — h over chunk + S = sum(delta) ----------------
__global__ __launch_bounds__(192) void k4_scanA(
    const float* __restrict__ xconv, const float* __restrict__ XDK,
    const float* __restrict__ dtw, const float* __restrict__ dtb,
    const float* __restrict__ A_log,
    float* __restrict__ Sarr, float* __restrict__ Q)
{
    int blk = blockIdx.x;              // bk*NC + c
    int c  = blk & (NC - 1);
    int bk = blk >> 7;
    int k  = bk & 3;
    int b  = bk >> 2;
    int d  = threadIdx.x;
    float dw[RNK];
    #pragma unroll
    for (int r = 0; r < RNK; r++) dw[r] = dtw[((size_t)k*DIN + d)*RNK + r];
    float bias = dtb[k*DIN + d];
    float A[NST];
    #pragma unroll
    for (int n = 0; n < NST; n++) A[n] = -__expf(A_log[((size_t)k*DIN + d)*NST + n]);
    bool fastA = true;
    #pragma unroll
    for (int n = 1; n < NST; n++)
        fastA = fastA && (fabsf(A[n] - (float)(n+1)*A[0]) <= 1e-4f*(float)(n+1));

    float h[NST];
    #pragma unroll
    for (int n = 0; n < NST; n++) h[n] = 0.f;
    float S = 0.f;

    size_t rb = ((size_t)bk*LL + c*CH)*CPK;
    if (fastA) {
        #pragma unroll 2
        for (int step = 0; step < CH; step++) {
            const float* rec = XDK + rb + step*CPK;
            float dl = bias;
            #pragma unroll
            for (int r = 0; r < RNK; r++) dl += rec[32 + r] * dw[r];
            dl = (dl > 20.f) ? dl : __logf(1.f + __expf(dl));
            int l = c*CH + step;
            float uu = xconv[((size_t)b*LL + pos_of(k, l))*DIN + d];
            float du = dl * uu;
            S += dl;
            float e1 = __expf(dl * A[0]);
            float e2 = e1*e1, e4 = e2*e2;
            float p0 = e1, p1 = e2, p2 = e2*e1, p3 = e4;
            #pragma unroll
            for (int g = 0; g < 4; g++) {
                h[4*g+0] = p0*h[4*g+0] + du*rec[4*g+0];
                h[4*g+1] = p1*h[4*g+1] + du*rec[4*g+1];
                h[4*g+2] = p2*h[4*g+2] + du*rec[4*g+2];
                h[4*g+3] = p3*h[4*g+3] + du*rec[4*g+3];
                if (g < 3) { p0 *= e4; p1 *= e4; p2 *= e4; p3 *= e4; }
            }
        }
    } else {
        #pragma unroll 2
        for (int step = 0; step < CH; step++) {
            const float* rec = XDK + rb + step*CPK;
            float dl = bias;
            #pragma unroll
            for (int r = 0; r < RNK; r++) dl += rec[32 + r] * dw[r];
            dl = (dl > 20.f) ? dl : __logf(1.f + __expf(dl));
            int l = c*CH + step;
            float uu = xconv[((size_t)b*LL + pos_of(k, l))*DIN + d];
            float du = dl * uu;
            S += dl;
            #pragma unroll
            for (int n = 0; n < NST; n++) {
                float a = __expf(dl * A[n]);
                h[n] = a*h[n] + du*rec[n];
            }
        }
    }
    Sarr[(size_t)blk*DIN + d] = S;
    size_t qb = (size_t)blk*NST*DIN + d;
    #pragma unroll
    for (int n = 0; n < NST; n++) Q[qb + n*DIN] = h[n];
}

// ---------------- K5: compose chunk transfers; Q becomes per-chunk init state ----------------
__global__ __launch_bounds__(256) void k5_scanB(
    const float* __restrict__ A_log, const float* __restrict__ Sarr,
    float* __restrict__ Q)
{
    int idx = blockIdx.x*256 + threadIdx.x;
    if (idx >= BB*KD*NST*DIN) return;
    int d = idx % DIN;
    int rest = idx / DIN;
    int n = rest % NST; rest /= NST;
    int k = rest & 3;
    int b = rest >> 2;
    int bk = b*KD + k;
    float A = -__expf(A_log[((size_t)k*DIN + d)*NST + n]);
    size_t qstride = (size_t)NST*DIN;
    size_t qbase = (size_t)bk*NC*qstride + n*DIN + d;
    size_t sbase = (size_t)bk*NC*DIN + d;
    float h = 0.f;
    #pragma unroll 4
    for (int c = 0; c < NC; c++) {
        float s = Sarr[sbase + c*DIN];
        float q = Q[qbase + c*qstride];
        Q[qbase + c*qstride] = h;
        h = __expf(A*s)*h + q;
    }
}

// ---------------- K6: scan pass C — replay, emit y at SPATIAL position ----------------
__global__ __launch_bounds__(192) void k6_scanC(
    const float* __restrict__ xconv, const float* __restrict__ XDK,
    const float* __restrict__ dtw, const float* __restrict__ dtb,
    const float* __restrict__ A_log, const float* __restrict__ Ds,
    const float* __restrict__ Q, float* __restrict__ outy)
{
    int blk = blockIdx.x;
    int c  = blk & (NC - 1);
    int bk = blk >> 7;
    int k  = bk & 3;
    int b  = bk >> 2;
    int d  = threadIdx.x;
    float dw[RNK];
    #pragma unroll
    for (int r = 0; r < RNK; r++) dw[r] = dtw[((size_t)k*DIN + d)*RNK + r];
    float bias = dtb[k*DIN + d];
    float A[NST];
    #pragma unroll
    for (int n = 0; n < NST; n++) A[n] = -__expf(A_log[((size_t)k*DIN + d)*NST + n]);
    bool fastA = true;
    #pragma unroll
    for (int n = 1; n < NST; n++)
        fastA = fastA && (fabsf(A[n] - (float)(n+1)*A[0]) <= 1e-4f*(float)(n+1));
    float h[NST];
    size_t qb = (size_t)blk*NST*DIN + d;
    #pragma unroll
    for (int n = 0; n < NST; n++) h[n] = Q[qb + n*DIN];
    float Dv = Ds[k*DIN + d];

    size_t rb = ((size_t)bk*LL + c*CH)*CPK;
    if (fastA) {
        #pragma unroll 2
        for (int step = 0; step < CH; step++) {
            const float* rec = XDK + rb + step*CPK;
            float dl = bias;
            #pragma unroll
            for (int r = 0; r < RNK; r++) dl += rec[32 + r] * dw[r];
            dl = (dl > 20.f) ? dl : __logf(1.f + __expf(dl));
            int l = c*CH + step;
            int sp = pos_of(k, l);
            float uu = xconv[((size_t)b*LL + sp)*DIN + d];
            float du = dl * uu;
            float e1 = __expf(dl * A[0]);
            float e2 = e1*e1, e4 = e2*e2;
            float p0 = e1, p1 = e2, p2 = e2*e1, p3 = e4;
            float yv = 0.f;
            #pragma unroll
            for (int g = 0; g < 4; g++) {
                h[4*g+0] = p0*h[4*g+0] + du*rec[4*g+0];
                h[4*g+1] = p1*h[4*g+1] + du*rec[4*g+1];
                h[4*g+2] = p2*h[4*g+2] + du*rec[4*g+2];
                h[4*g+3] = p3*h[4*g+3] + du*rec[4*g+3];
                yv += h[4*g+0]*rec[16+4*g+0] + h[4*g+1]*rec[16+4*g+1]
                    + h[4*g+2]*rec[16+4*g+2] + h[4*g+3]*rec[16+4*g+3];
                if (g < 3) { p0 *= e4; p1 *= e4; p2 *= e4; p3 *= e4; }
            }
            outy[((size_t)bk*LL + sp)*DIN + d] = yv + Dv*uu;
        }
    } else {
        #pragma unroll 2
        for (int step = 0; step < CH; step++) {
            const float* rec = XDK + rb + step*CPK;
            float dl = bias;
            #pragma unroll
            for (int r = 0; r < RNK; r++) dl += rec[32 + r] * dw[r];
            dl = (dl > 20.f) ? dl : __logf(1.f + __expf(dl));
            int l = c*CH + step;
            int sp = pos_of(k, l);
            float uu = xconv[((size_t)b*LL + sp)*DIN + d];
            float du = dl * uu;
            float yv = 0.f;
            #pragma unroll
            for (int n = 0; n < NST; n++) {
                float a = __expf(dl * A[n]);
                h[n] = a*h[n] + du*rec[n];
                yv += h[n] * rec[16 + n];
            }
            outy[((size_t)bk*LL + sp)*DIN + d] = yv + Dv*uu;
        }
    }
}

// ---------------- K7: combine (coalesced), LN(192), gate, out_proj, residual ----------------
__global__ __launch_bounds__(256) void k7_out(
    const float* __restrict__ outy, const float* __restrict__ zbuf,
    const float* __restrict__ diff, const float* __restrict__ onw,
    const float* __restrict__ onb, const float* __restrict__ WoutT,
    float* __restrict__ out)
{
    __shared__ float gT[192*65];
    __shared__ float ps1[4*64], ps2[4*64];
    __shared__ float mus[64], rss[64];
    int t = threadIdx.x;
    int ptile = blockIdx.x >> 1, chalf = blockIdx.x & 1;
    int p0 = ptile*64;
    int b = p0 >> 12;
    int l0 = p0 & (LL - 1);
    const size_t seg = (size_t)LL*DIN;
    size_t base = ((size_t)(b*KD)*LL + l0)*DIN;

    #pragma unroll
    for (int s = 0; s < 48; s++) {
        int i = t + 256*s;
        float yc = outy[base + i] + outy[base + seg + i]
                 + outy[base + 2*seg + i] + outy[base + 3*seg + i];
        int pos = i / 192, ch = i - pos*192;
        gT[ch*65 + pos] = yc;
    }
    __syncthreads();
    {
        int pos = t & 63, part = t >> 6;
        float s1 = 0.f, s2 = 0.f;
        #pragma unroll
        for (int m = 0; m < 48; m++) {
            float v = gT[(part*48 + m)*65 + pos];
            s1 += v; s2 += v*v;
        }
        ps1[part*64 + pos] = s1; ps2[part*64 + pos] = s2;
    }
    __syncthreads();
    if (t < 64) {
        float S1 = ps1[t] + ps1[64+t] + ps1[128+t] + ps1[192+t];
        float S2 = ps2[t] + ps2[64+t] + ps2[128+t] + ps2[192+t];
        float mu = S1 * (1.f/192.f);
        float var = S2 * (1.f/192.f) - mu*mu;
        mus[t] = mu; rss[t] = rsqrtf(var + 1e-5f);
    }
    __syncthreads();
    #pragma unroll
    for (int s = 0; s < 48; s++) {
        int i = t + 256*s;
        int pos = i / 192, ch = i - pos*192;
        float v = gT[ch*65 + pos];
        float yn = (v - mus[pos]) * rss[pos] * onw[ch] + onb[ch];
        float z = zbuf[(size_t)p0*DIN + i];
        gT[ch*65 + pos] = yn * silu_f(z);
    }
    __syncthreads();

    int w = __builtin_amdgcn_readfirstlane(t >> 6);
    int lane = t & 63;
    int c0 = chalf*48 + w*12;
    const float* wp = WoutT + c0;
    float acc[12];
    #pragma unroll
    for (int cc = 0; cc < 12; cc++) acc[cc] = 0.f;
    #pragma unroll 2
    for (int j = 0; j < 192; j++) {
        float u = gT[j*65 + lane];
        const float* wrow = wp + j*96;
        #pragma unroll
        for (int cc = 0; cc < 12; cc++) acc[cc] += u * wrow[cc];
    }
    size_t p = (size_t)(p0 + lane);
    #pragma unroll
    for (int q = 0; q < 3; q++) {
        float4 dv = *(const float4*)&diff[p*96 + c0 + 4*q];
        *(float4*)&out[p*96 + c0 + 4*q] =
            make_float4(acc[4*q] + dv.x, acc[4*q+1] + dv.y, acc[4*q+2] + dv.z, acc[4*q+3] + dv.w);
    }
}

extern "C" void kernel_launch(void* const* d_in, const int* in_sizes, int n_in,
                              void* d_out, int out_size, void* d_ws, size_t ws_size,
                              hipStream_t stream)
{
    const float* x       = (const float*)d_in[0];
    const float* y       = (const float*)d_in[1];
    const float* ln_w    = (const float*)d_in[2];
    const float* ln_b    = (const float*)d_in[3];
    const float* in_proj = (const float*)d_in[4];
    const float* conv_w  = (const float*)d_in[5];
    const float* conv_b  = (const float*)d_in[6];
    const float* x_proj  = (const float*)d_in[7];
    const float* dt_w    = (const float*)d_in[8];
    const float* dt_b    = (const float*)d_in[9];
    const float* A_log   = (const float*)d_in[10];
    const float* Ds      = (const float*)d_in[11];
    const float* onw     = (const float*)d_in[12];
    const float* onb     = (const float*)d_in[13];
    const float* out_w   = (const float*)d_in[14];
    float* out = (float*)d_out;

    float* ws    = (float*)d_ws;
    float* diff  = ws;                       // 786432
    float* zbuf  = diff  + 786432;           // 1572864
    float* xm    = zbuf  + 1572864;          // 1572864
    float* xconv = xm    + 1572864;          // 1572864
    float* XDK   = xconv + 1572864;          // 1572864
    float* outy  = XDK   + 1572864;          // 6291456
    float* Qbuf  = outy  + 6291456;          // 3145728 (1024 blk x 16 x 192)
    float* Sarr  = Qbuf  + 6291456;          // 196608
    float* WinT  = Sarr  + 393216;           // 36864
    float* WoutT = WinT  + 36864;            // 18432
    float* wT3   = WoutT + 18432;            // 36864

    const int BL = BB * LL;                  // 8192

    hipLaunchKernelGGL(k0_prep, dim3(144), dim3(256), 0, stream,
                       in_proj, out_w, x_proj, WinT, WoutT, wT3);
    hipLaunchKernelGGL(k1_ln_inproj, dim3(BL/64*2), dim3(1024), 0, stream,
                       x, y, ln_w, ln_b, WinT, diff, xm, zbuf);
    hipLaunchKernelGGL(k2_conv, dim3(BL), dim3(DIN), 0, stream,
                       xm, conv_w, conv_b, xconv);
    hipLaunchKernelGGL(k3_xproj, dim3(BL/64*2), dim3(512), 0, stream,
                       xconv, wT3, XDK);
    hipLaunchKernelGGL(k4_scanA, dim3(BB*KD*NC), dim3(DIN), 0, stream,
                       xconv, XDK, dt_w, dt_b, A_log, Sarr, Qbuf);
    hipLaunchKernelGGL(k5_scanB, dim3((BB*KD*NST*DIN + 255)/256), dim3(256), 0, stream,
                       A_log, Sarr, Qbuf);
    hipLaunchKernelGGL(k6_scanC, dim3(BB*KD*NC), dim3(DIN), 0, stream,
                       xconv, XDK, dt_w, dt_b, A_log, Ds, Qbuf, outy);
    hipLaunchKernelGGL(k7_out, dim3(BL/64*2), dim3(256), 0, stream,
                       outy, zbuf, diff, onw, onb, WoutT, out);
}